// Round 1
// baseline (356.831 us; speedup 1.0000x reference)
//
#include <hip/hip_runtime.h>
#include <hip/hip_bf16.h>

typedef unsigned int u32;

#define BN 32
#define CC 192
#define HH 64
#define WW 64
#define HWSZ (HH*WW)          // 4096
#define OHH 32
#define OWW 32
#define NVALID_SCALE 131072.0f // BN*HH*WW per channel

// ---------------- K1: per-(c,n) partial sum / sumsq ----------------
__global__ __launch_bounds__(256) void k_stats(const float* __restrict__ x,
                                               float* __restrict__ partial) {
    int b = blockIdx.x;            // b = c*32 + n
    int c = b >> 5, n = b & 31;
    const float4* p = (const float4*)(x + ((size_t)(n * CC + c) << 12));
    int tid = threadIdx.x;
    float s = 0.f, s2 = 0.f;
#pragma unroll
    for (int k = 0; k < 4; ++k) {
        float4 f = p[tid + 256 * k];
        s  += f.x + f.y + f.z + f.w;
        s2 += f.x * f.x + f.y * f.y + f.z * f.z + f.w * f.w;
    }
#pragma unroll
    for (int off = 32; off > 0; off >>= 1) {
        s  += __shfl_down(s, off, 64);
        s2 += __shfl_down(s2, off, 64);
    }
    __shared__ float red[8];
    int wv = tid >> 6, ln = tid & 63;
    if (ln == 0) { red[wv * 2] = s; red[wv * 2 + 1] = s2; }
    __syncthreads();
    if (tid == 0) {
        partial[b * 2]     = red[0] + red[2] + red[4] + red[6];
        partial[b * 2 + 1] = red[1] + red[3] + red[5] + red[7];
    }
}

// ---------------- K2: finalize BN coefs (both branches) ----------------
__global__ __launch_bounds__(256) void k_coef(const float* __restrict__ partial,
        const float* __restrict__ g1, const float* __restrict__ b1,
        const float* __restrict__ g2, const float* __restrict__ b2,
        float* __restrict__ coef) {
    int c = threadIdx.x;
    if (c >= CC) return;
    float S = 0.f, S2 = 0.f;
    for (int n = 0; n < BN; ++n) {
        S  += partial[(c * BN + n) * 2];
        S2 += partial[(c * BN + n) * 2 + 1];
    }
    const float inv = 1.0f / NVALID_SCALE;
    float mu  = S * inv;
    float var = S2 * inv - mu * mu;
    float r   = 1.0f / sqrtf(var + 1e-5f);
    float s1 = g1[c] * r, t1 = b1[c] - mu * s1;
    float s2 = g2[c] * r, t2 = b2[c] - mu * s2;
    ((float4*)coef)[c] = make_float4(s1, t1, s2, t2);
}

// ---------------- K3: binarize + bit-pack activations, both branches ----------------
// act layout: [n][h*64+w][12 u32 words]; words 0..5 branch1 (bit = ch&31, word = ch>>5),
// words 6..11 branch2. bit set <=> h > 0 (sign +1).
__global__ __launch_bounds__(256) void k_pack_act(const float* __restrict__ x,
        const float* __restrict__ coef, u32* __restrict__ act) {
    int n = blockIdx.x >> 4, tile = blockIdx.x & 15;
    int px = tile * 256 + threadIdx.x;
    const float* xb = x + (size_t)n * CC * HWSZ + px;
    const float4* c4 = (const float4*)coef;
    u32 pk[12];
#pragma unroll
    for (int i = 0; i < 12; ++i) pk[i] = 0;
    for (int ch = 0; ch < CC; ++ch) {
        float v = xb[(size_t)ch * HWSZ];
        float4 cf = c4[ch];
        u32 bit = 1u << (ch & 31);
        int w = ch >> 5;
        if (v * cf.x + cf.y > 0.f) pk[w] |= bit;
        if (v * cf.z + cf.w > 0.f) pk[6 + w] |= bit;
    }
    uint4* dst = (uint4*)(act + (size_t)(n * HWSZ + px) * 12);
    dst[0] = make_uint4(pk[0], pk[1], pk[2], pk[3]);
    dst[1] = make_uint4(pk[4], pk[5], pk[6], pk[7]);
    dst[2] = make_uint4(pk[8], pk[9], pk[10], pk[11]);
}

// ---------------- K4: sign-pack weights ----------------
// wp layout: [(br*192 + oc)*9 + kh*3+kw]*6 + w  (bit ic&31 of word ic>>5)
__global__ __launch_bounds__(256) void k_pack_w(const float* __restrict__ w1,
        const float* __restrict__ w2, u32* __restrict__ wp) {
    int i = blockIdx.x * 256 + threadIdx.x;
    if (i >= 2 * CC * 54) return;
    int w   = i % 6;
    int pos = (i / 6) % 9;
    int oc  = (i / 54) % CC;
    const float* W = (i >= CC * 54) ? w2 : w1;
    u32 word = 0;
#pragma unroll
    for (int b = 0; b < 32; ++b) {
        float v = W[((size_t)oc * CC + (w * 32 + b)) * 9 + pos];
        if (v > 0.f) word |= (1u << b);
    }
    wp[i] = word;
}

// ---------------- K5: XNOR conv + bias + relu + avgpool shortcut ----------------
// grid: b = ((n*32 + oh)*2 + half); block 256 = 32 ow-lanes x 8 oc-lanes;
// each oc-lane handles 12 oc of this half (96 oc), both branches.
__global__ __launch_bounds__(256) void k_conv(
        const u32* __restrict__ act, const u32* __restrict__ wp,
        const float* __restrict__ x,
        const float* __restrict__ bias1, const float* __restrict__ bias2,
        float* __restrict__ out) {
    __shared__ u32 wlds[2 * 96 * 54];   // 41.4 KB
    int b    = blockIdx.x;
    int half = b & 1;
    int oh   = (b >> 1) & 31;
    int n    = b >> 6;
    int tid  = threadIdx.x;
    // cooperative weight staging: both branches, 96 oc of this half
    for (int i = tid; i < 2 * 96 * 54; i += 256) {
        int br = i / (96 * 54);
        int r  = i - br * 96 * 54;
        wlds[i] = wp[(br * CC + half * 96) * 54 + r];
    }
    __syncthreads();
    int ow  = tid & 31;
    int ocl = tid >> 5;                     // 0..7
    u32 mask0 = (ow == 0) ? 0u : 0xFFFFFFFFu;  // kw=0 column invalid at ow==0
    int cv = (ow == 0) ? 2 : 3;
    int rv = (oh == 0) ? 2 : 3;
    int acc1[12], acc2[12];
#pragma unroll
    for (int j = 0; j < 12; ++j) { acc1[j] = 0; acc2[j] = 0; }
#pragma unroll
    for (int kh = 0; kh < 3; ++kh) {
        int ih = 2 * oh - 1 + kh;
        if (ih < 0) continue;               // block-uniform (oh==0 only)
        u32 aw[3][12];
#pragma unroll
        for (int kw = 0; kw < 3; ++kw) {
            int px = 2 * ow - 1 + kw;
            if (px < 0) px = 0;             // garbage read, masked by mask0
            const uint4* p = (const uint4*)(act + (size_t)(n * HWSZ + ih * WW + px) * 12);
            uint4 q0 = p[0], q1 = p[1], q2 = p[2];
            aw[kw][0] = q0.x; aw[kw][1] = q0.y; aw[kw][2]  = q0.z; aw[kw][3]  = q0.w;
            aw[kw][4] = q1.x; aw[kw][5] = q1.y; aw[kw][6]  = q1.z; aw[kw][7]  = q1.w;
            aw[kw][8] = q2.x; aw[kw][9] = q2.y; aw[kw][10] = q2.z; aw[kw][11] = q2.w;
        }
#pragma unroll
        for (int j = 0; j < 12; ++j) {
            int oo = ocl * 12 + j;
            const u32* w1p = &wlds[oo * 54 + kh * 18];
            const u32* w2p = &wlds[(96 + oo) * 54 + kh * 18];
            int p1 = 0, p2 = 0;
#pragma unroll
            for (int w = 0; w < 6; ++w) {
                p1 += __popc((aw[0][w]     ^ w1p[w]) & mask0);
                p2 += __popc((aw[0][6 + w] ^ w2p[w]) & mask0);
                p1 += __popc(aw[1][w]     ^ w1p[6 + w]);
                p2 += __popc(aw[1][6 + w] ^ w2p[6 + w]);
                p1 += __popc(aw[2][w]     ^ w1p[12 + w]);
                p2 += __popc(aw[2][6 + w] ^ w2p[12 + w]);
            }
            acc1[j] += p1; acc2[j] += p2;
        }
    }
    float base = (float)(CC * rv * cv);     // 192 * n_valid
#pragma unroll
    for (int j = 0; j < 12; ++j) {
        int oc = half * 96 + ocl * 12 + j;
        const float* xp = x + (((size_t)n * CC + oc) * HH + 2 * oh) * WW + 2 * ow;
        float2 r0 = *(const float2*)xp;
        float2 r1 = *(const float2*)(xp + WW);
        float sc = (r0.x + r0.y + r1.x + r1.y) * 0.25f;
        float y1 = base - 2.0f * (float)acc1[j] + bias1[oc];
        float y2 = base - 2.0f * (float)acc2[j] + bias2[oc];
        out[(((size_t)n * 384 + oc) * OHH + oh) * OWW + ow]       = fmaxf(y1, 0.f) + sc;
        out[(((size_t)n * 384 + 192 + oc) * OHH + oh) * OWW + ow] = fmaxf(y2, 0.f) + sc;
    }
}

extern "C" void kernel_launch(void* const* d_in, const int* in_sizes, int n_in,
                              void* d_out, int out_size, void* d_ws, size_t ws_size,
                              hipStream_t stream) {
    const float* x     = (const float*)d_in[0];
    const float* g1    = (const float*)d_in[1];
    const float* b1    = (const float*)d_in[2];
    const float* w1    = (const float*)d_in[3];
    const float* bias1 = (const float*)d_in[4];
    const float* g2    = (const float*)d_in[5];
    const float* b2    = (const float*)d_in[6];
    const float* w2    = (const float*)d_in[7];
    const float* bias2 = (const float*)d_in[8];
    float* out = (float*)d_out;
    char* ws = (char*)d_ws;
    // ws layout (all regions fully written before read; no memset needed):
    float* partial = (float*)(ws);            // 12288 f  (48 KB)
    float* coef    = (float*)(ws + 49152);    // 768 f    (3 KB)
    u32*   wp      = (u32*)  (ws + 52224);    // 20736 u  (81 KB)
    u32*   act     = (u32*)  (ws + 135168);   // 1572864 u (6 MB)

    hipLaunchKernelGGL(k_stats,    dim3(CC * BN), dim3(256), 0, stream, x, partial);
    hipLaunchKernelGGL(k_coef,     dim3(1),       dim3(256), 0, stream, partial, g1, b1, g2, b2, coef);
    hipLaunchKernelGGL(k_pack_act, dim3(BN * 16), dim3(256), 0, stream, x, coef, act);
    hipLaunchKernelGGL(k_pack_w,   dim3(81),      dim3(256), 0, stream, w1, w2, wp);
    hipLaunchKernelGGL(k_conv,     dim3(BN * OHH * 2), dim3(256), 0, stream, act, wp, x, bias1, bias2, out);
}

// Round 2
// 244.414 us; speedup vs baseline: 1.4599x; 1.4599x over previous
//
#include <hip/hip_runtime.h>
#include <hip/hip_bf16.h>

typedef unsigned int u32;

#define BN 32
#define CC 192
#define HH 64
#define WW 64
#define HWSZ (HH*WW)            // 4096
#define OHH 32
#define OWW 32
#define NVALID_SCALE 131072.0f  // BN*HH*WW per channel
#define PLW 65                  // halo plane width (iw+1 in [0,64])
#define PLSZ (PLW*PLW)          // 4225 words per plane
#define NPLANE (12*BN)          // 2 br * 6 words * 32 n = 384 planes

// ---------------- K1: per-(c,n) partial sum / sumsq ----------------
__global__ __launch_bounds__(256) void k_stats(const float* __restrict__ x,
                                               float* __restrict__ partial) {
    int b = blockIdx.x;            // b = c*32 + n
    int c = b >> 5, n = b & 31;
    const float4* p = (const float4*)(x + ((size_t)(n * CC + c) << 12));
    int tid = threadIdx.x;
    float s = 0.f, s2 = 0.f;
#pragma unroll
    for (int k = 0; k < 4; ++k) {
        float4 f = p[tid + 256 * k];
        s  += f.x + f.y + f.z + f.w;
        s2 += f.x * f.x + f.y * f.y + f.z * f.z + f.w * f.w;
    }
#pragma unroll
    for (int off = 32; off > 0; off >>= 1) {
        s  += __shfl_down(s, off, 64);
        s2 += __shfl_down(s2, off, 64);
    }
    __shared__ float red[8];
    int wv = tid >> 6, ln = tid & 63;
    if (ln == 0) { red[wv * 2] = s; red[wv * 2 + 1] = s2; }
    __syncthreads();
    if (tid == 0) {
        partial[b * 2]     = red[0] + red[2] + red[4] + red[6];
        partial[b * 2 + 1] = red[1] + red[3] + red[5] + red[7];
    }
}

// ---------------- K2: finalize BN coefs (both branches), 1 block/channel ----------------
__global__ __launch_bounds__(64) void k_coef(const float* __restrict__ partial,
        const float* __restrict__ g1, const float* __restrict__ b1,
        const float* __restrict__ g2, const float* __restrict__ b2,
        float* __restrict__ coef) {
    int c = blockIdx.x;
    int t = threadIdx.x;
    int half = t >> 5, i = t & 31;
    float v = partial[(c * 32 + i) * 2 + half];
#pragma unroll
    for (int off = 16; off > 0; off >>= 1) v += __shfl_down(v, off, 32);
    float S2 = __shfl(v, 32, 64);   // lane 32 holds sumsq reduction
    if (t == 0) {
        float S = v;
        const float inv = 1.0f / NVALID_SCALE;
        float mu  = S * inv;
        float var = S2 * inv - mu * mu;
        float r   = 1.0f / sqrtf(var + 1e-5f);
        float s1 = g1[c] * r, t1 = b1[c] - mu * s1;
        float s2 = g2[c] * r, t2 = b2[c] - mu * s2;
        ((float4*)coef)[c] = make_float4(s1, t1, s2, t2);
    }
}

// ---------------- K3: sign-pack weights + edge popcount sums ----------------
// wp layout: [(br*192+oc)*54 + (kh*3+kw)*6 + w6], bit b = ic (w6*32+b)
// wsum layout: [(br*192+oc)*4] = {Wrow0, Wcol0, Wcorner, 0}
__global__ __launch_bounds__(256) void k_pack_w(const float* __restrict__ w1,
        const float* __restrict__ w2, u32* __restrict__ wp, u32* __restrict__ wsum) {
    __shared__ float wl[CC * 9];
    __shared__ u32 ww[54];
    int b  = blockIdx.x;
    int br = b / CC, oc = b - br * CC;
    const float* W = (br ? w2 : w1) + (size_t)oc * CC * 9;
    int tid = threadIdx.x;
    for (int i = tid; i < CC * 9; i += 256) wl[i] = W[i];
    __syncthreads();
    if (tid < 54) {
        int w6 = tid % 6, pos = tid / 6;
        u32 word = 0;
#pragma unroll
        for (int bb = 0; bb < 32; ++bb) {
            if (wl[(w6 * 32 + bb) * 9 + pos] > 0.f) word |= (1u << bb);
        }
        wp[(size_t)b * 54 + tid] = word;
        ww[tid] = word;
    }
    __syncthreads();
    if (tid == 0) {
        int Wt[9];
#pragma unroll
        for (int t = 0; t < 9; ++t) {
            int s = 0;
#pragma unroll
            for (int w6 = 0; w6 < 6; ++w6) s += __popc(ww[t * 6 + w6]);
            Wt[t] = s;
        }
        wsum[b * 4 + 0] = (u32)(Wt[0] + Wt[1] + Wt[2]);  // top row kh=0
        wsum[b * 4 + 1] = (u32)(Wt[0] + Wt[3] + Wt[6]);  // left col kw=0
        wsum[b * 4 + 2] = (u32)Wt[0];                    // corner
        wsum[b * 4 + 3] = 0;
    }
}

// ---------------- K4: zero act halo (row 0 and col 0 of each plane) ----------------
__global__ __launch_bounds__(192) void k_halo(u32* __restrict__ act) {
    u32* pl = act + (size_t)blockIdx.x * PLSZ;
    int t = threadIdx.x;
    if (t < PLW) pl[t] = 0;                       // row ih=-1
    else if (t < 2 * PLW - 1) pl[(t - PLW + 1) * PLW] = 0;  // col iw=-1 (rows 1..64)
}

// ---------------- K5: binarize + bit-pack activations, word-planar + halo ----------------
// act plane index p = (br*6 + w6)*32 + n; word at [(ih+1)*65 + (iw+1)]
__global__ __launch_bounds__(256) void k_pack_act(const float* __restrict__ x,
        const float* __restrict__ coef, u32* __restrict__ act) {
    int tile = blockIdx.x;          // 0..511: n*16 + pxt
    int g    = blockIdx.y;          // word group 0..5
    int n = tile >> 4, pxt = tile & 15;
    int px = pxt * 256 + threadIdx.x;
    int h = px >> 6, w = px & 63;
    const float*  xb = x + (size_t)n * CC * HWSZ + px;
    const float4* c4 = (const float4*)coef;
    u32 pk1 = 0, pk2 = 0;
#pragma unroll 8
    for (int bb = 0; bb < 32; ++bb) {
        int ch = g * 32 + bb;
        float v = xb[(size_t)ch * HWSZ];
        float4 cf = c4[ch];
        u32 bit = 1u << bb;
        if (v * cf.x + cf.y > 0.f) pk1 |= bit;
        if (v * cf.z + cf.w > 0.f) pk2 |= bit;
    }
    size_t off = (size_t)(h + 1) * PLW + (w + 1);
    act[((size_t)(0 * 6 + g) * BN + n) * PLSZ + off] = pk1;
    act[((size_t)(1 * 6 + g) * BN + n) * PLSZ + off] = pk2;
}

// ---------------- K6: XNOR conv + bias + relu + avgpool shortcut ----------------
// grid 2048 = 512 px-tiles * 4; block = 4 waves; wave = 64 px (2 oh rows x 32 ow),
// wave handles 12 oc (both branches). Weights via wave-uniform scalar loads (SGPRs).
__global__ __launch_bounds__(256) void k_conv(
        const u32* __restrict__ act, const u32* __restrict__ wp,
        const u32* __restrict__ wsum, const float* __restrict__ x,
        const float* __restrict__ bias1, const float* __restrict__ bias2,
        float* __restrict__ out) {
    int b    = blockIdx.x;
    int tile = b >> 2;                  // (n, ohp)
    int n    = tile >> 4, ohp = tile & 15;
    int wid  = __builtin_amdgcn_readfirstlane((int)(threadIdx.x >> 6));
    int ocbase = ((b & 3) * 4 + wid) * 12;   // 16 groups of 12 oc
    int lane = threadIdx.x & 63;
    int ow = lane & 31, lh = lane >> 5;
    int oh = 2 * ohp + lh;
    int lbase = (2 * oh) * PLW + 2 * ow;     // tap (kh=0,kw=0) offset within plane
    int topE  = (oh == 0), leftE = (ow == 0);
    int nv192 = CC * ((topE ? 2 : 3) * (leftE ? 2 : 3));
    float sc[12];
#pragma unroll 1
    for (int br = 0; br < 2; ++br) {
        // act fragments: a[t*6+w6]
        u32 a[54];
        const u32* ap = act + ((size_t)(br * 6) * BN + n) * PLSZ + lbase;
#pragma unroll
        for (int w6 = 0; w6 < 6; ++w6) {
            const u32* app = ap + (size_t)w6 * (BN * PLSZ);
#pragma unroll
            for (int t = 0; t < 9; ++t) {
                a[t * 6 + w6] = app[(t / 3) * PLW + (t % 3)];
            }
        }
        const u32*   wqb = wp   + (size_t)(br * CC + ocbase) * 54;
        const u32*   wsb = wsum + (size_t)(br * CC + ocbase) * 4;
        const float* bsp = (br ? bias2 : bias1) + ocbase;
#pragma unroll 2
        for (int j = 0; j < 12; ++j) {
            u32 wv[54];
#pragma unroll
            for (int k = 0; k < 54; ++k) wv[k] = wqb[j * 54 + k];
            int p = 0;
#pragma unroll
            for (int k = 0; k < 54; ++k) p += __popc(a[k] ^ wv[k]);
            int Wr = (int)wsb[j * 4], Wc = (int)wsb[j * 4 + 1], Wk = (int)wsb[j * 4 + 2];
            int corr = (topE ? Wr : 0) + (leftE ? Wc : 0) - ((topE & leftE) ? Wk : 0);
            int dot = nv192 - 2 * p + 2 * corr;
            int oc = ocbase + j;
            float y = (float)dot + bsp[j];
            if (br == 0) {
                const float* xp = x + (((size_t)n * CC + oc) * HH + 2 * oh) * WW + 2 * ow;
                float2 r0 = *(const float2*)xp;
                float2 r1 = *(const float2*)(xp + WW);
                sc[j] = (r0.x + r0.y + r1.x + r1.y) * 0.25f;
            }
            out[((size_t)(n * 384 + br * CC + oc) * OHH + oh) * OWW + ow] =
                fmaxf(y, 0.f) + sc[j];
        }
    }
}

extern "C" void kernel_launch(void* const* d_in, const int* in_sizes, int n_in,
                              void* d_out, int out_size, void* d_ws, size_t ws_size,
                              hipStream_t stream) {
    const float* x     = (const float*)d_in[0];
    const float* g1    = (const float*)d_in[1];
    const float* b1    = (const float*)d_in[2];
    const float* w1    = (const float*)d_in[3];
    const float* bias1 = (const float*)d_in[4];
    const float* g2    = (const float*)d_in[5];
    const float* b2    = (const float*)d_in[6];
    const float* w2    = (const float*)d_in[7];
    const float* bias2 = (const float*)d_in[8];
    float* out = (float*)d_out;
    char* ws = (char*)d_ws;
    // ws layout (all regions fully written before read; halo zeroed by k_halo):
    float* partial = (float*)(ws);             // 12288 f   -> 49152 B
    float* coef    = (float*)(ws + 49152);     // 768 f     -> 3072 B
    u32*   wp      = (u32*)  (ws + 52224);     // 20736 u32 -> 82944 B
    u32*   wsum    = (u32*)  (ws + 135168);    // 1536 u32  -> 6144 B
    u32*   act     = (u32*)  (ws + 141312);    // 384*4225 u32 -> 6489600 B

    hipLaunchKernelGGL(k_stats,    dim3(CC * BN),      dim3(256), 0, stream, x, partial);
    hipLaunchKernelGGL(k_coef,     dim3(CC),           dim3(64),  0, stream, partial, g1, b1, g2, b2, coef);
    hipLaunchKernelGGL(k_pack_w,   dim3(2 * CC),       dim3(256), 0, stream, w1, w2, wp, wsum);
    hipLaunchKernelGGL(k_halo,     dim3(NPLANE),       dim3(192), 0, stream, act);
    hipLaunchKernelGGL(k_pack_act, dim3(512, 6),       dim3(256), 0, stream, x, coef, act);
    hipLaunchKernelGGL(k_conv,     dim3(BN * 16 * 4),  dim3(256), 0, stream, act, wp, wsum, x, bias1, bias2, out);
}